// Round 7
// baseline (356.889 us; speedup 1.0000x reference)
//
#include <hip/hip_runtime.h>
#include <math.h>

#define LMAX   5
#define MUL    128
#define NCH    4
#define NRAD   64
#define RBETA  180
#define RALPHA 359
#define NGRAPH 16
#define SH_DIM 36
#define EMB_DIM 4608
#define NIRR   768

#define GRID_BA (RBETA * RALPHA)          // 64620
#define NW21    21                        // (LMAX+1)(LMAX+2)/2 packed (l,m) weights
#define BTILE   4                         // beta rows per block; 4*359 floats = 359 float4 exactly
#define NBT     (RBETA / BTILE)           // 45

typedef float vfloat4 __attribute__((ext_vector_type(4)));

// out layout (floats): [0] coeffs 147456 | [1] pos 66170880 | [2] ang 1033920 | [3] rad 1024
#define OUT0_OFF 0
#define OUT1_OFF 147456
#define OUT2_OFF (147456 + 66170880)
#define OUT3_OFF (147456 + 66170880 + 1033920)

// ws layout (bytes): float tab[180*21] @ 0 (15120 B)
#define WS_TAB_OFF 0

// ---------------------------------------------------------------------------
// K0: SH weight-table init, 1 block, 256 threads. Thread i owns Gauss-Legendre
// node i of P_180 (independent fp64 Newton) and emits its 21 packed weights
//   tab[i][l(l+1)/2+m] = (m==0?1:sqrt2) * N_lm * P_lm(y_i)
// (Device-side — avoids pageable-host hipMemcpyAsync inside graph capture,
//  the suspected R6 container-failure trigger.)
__global__ __launch_bounds__(256)
void k_tab(float* __restrict__ tab)
{
    const int tid = threadIdx.x;
    __shared__ double rcp[RBETA];         // 1/(k+1)
    for (int k = tid; k < RBETA; k += 256) rcp[k] = 1.0 / (double)(k + 1);
    __syncthreads();
    const int i = tid;
    if (i >= RBETA) return;
    const double PI = 3.14159265358979323846;
    double x = -cos(PI * (i + 0.75) / (RBETA + 0.5));   // ascending node guess
    for (int it = 0; it < 4; ++it) {                    // 2 iters reach fp64 eps; 4 = margin
        double p0 = 1.0, p1 = x;
        for (int k = 1; k < RBETA; ++k) {
            double p2 = ((2.0 * k + 1.0) * x * p1 - (double)k * p0) * rcp[k];
            p0 = p1; p1 = p2;
        }
        double dp = RBETA * (x * p1 - p0) / (x * x - 1.0);
        x -= p1 / dp;
    }
    double P[LMAX + 1][LMAX + 1];
    P[0][0] = 1.0;
    double somx2 = sqrt(fmax(1.0 - x * x, 0.0));
    for (int m = 1; m <= LMAX; ++m) P[m][m] = -(2.0 * m - 1.0) * somx2 * P[m - 1][m - 1];
    for (int m = 0; m < LMAX; ++m)  P[m + 1][m] = (2.0 * m + 1.0) * x * P[m][m];
    for (int m = 0; m <= LMAX; ++m)
        for (int l = m + 2; l <= LMAX; ++l)
            P[l][m] = ((2.0 * l - 1.0) * x * P[l - 1][m] - (l + m - 1.0) * P[l - 2][m]) / (double)(l - m);
    const double FOURPI = 12.566370614359172;
    for (int l = 0; l <= LMAX; ++l) {
        for (int m = 0; m <= l; ++m) {
            double fr = 1.0;                       // (l-m)!/(l+m)!
            for (int k = l - m + 1; k <= l + m; ++k) fr /= (double)k;
            double N = sqrt((2.0 * l + 1.0) / FOURPI * fr);
            double w = N * P[l][m];
            if (m > 0) w *= 1.4142135623730951;
            tab[i * NW21 + l * (l + 1) / 2 + m] = (float)w;
        }
    }
}

// ---------------------------------------------------------------------------
// K1 (fused): one block per (beta-tile, graph). Each block redundantly
// recomputes its graph's small path (~43K MACs; weights L2-hot across the 720
// blocks), then Fourier-synthesizes 4 beta rows and streams all outputs.
// bt==0 blocks additionally write out0 (coeffs) and out3 (radial logits).
// Stores are regular cached float4 (R4 showed nt/bypass-L2 loses ~20 us).
__global__ __launch_bounds__(256)
void k_all(const float* __restrict__ tab,
           const float* __restrict__ ne, const float* __restrict__ sp,
           const float* __restrict__ wrad, const float* __restrict__ wm1,
           const float* __restrict__ wm2,
           const float* __restrict__ wa0, const float* __restrict__ wa1,
           const float* __restrict__ wa2, const float* __restrict__ wa3,
           const float* __restrict__ wa4, const float* __restrict__ wa5,
           const int* __restrict__ focus, const int* __restrict__ tspec,
           float* __restrict__ out0, float* __restrict__ out1,
           float* __restrict__ out2, float* __restrict__ out3)
{
    __shared__ float s0[MUL];
    __shared__ float rr[NRAD];
    __shared__ float hh[MUL];
    __shared__ float rl[NRAD];
    __shared__ float sang[NCH * SH_DIM];
    __shared__ float sW[BTILE][NW21];
    __shared__ float sF[BTILE][NCH][11];
    __shared__ float sRC[NRAD];
    __shared__ __align__(16) float sL[BTILE * RALPHA];   // 1436 floats

    const int bt  = blockIdx.x;          // 0..44
    const int g   = blockIdx.y;
    const int tid = threadIdx.x;
    const int fi  = focus[g];
    const int ts  = tspec[g];
    const float rs128 = 0.08838834764831845f;   // 1/sqrt(128)
    const float rs64  = 0.125f;                 // 1/sqrt(64)

    // ---- phase 0: loads independent of everything ----
    if (tid < BTILE * NW21)              // 84 threads
        sW[tid / NW21][tid % NW21] = tab[(bt * BTILE + tid / NW21) * NW21 + tid % NW21];
    if (tid >= 128 && tid < 128 + MUL)
        s0[tid - 128] = ne[(size_t)fi * EMB_DIM + (tid - 128)] * sp[ts * NIRR + (tid - 128)];
    __syncthreads();

    // ---- radial MLP chain ----
    if (tid < NRAD) {
        float acc = 0.f;
        for (int k = 0; k < MUL; ++k) acc += s0[k] * wrad[k * NRAD + tid];
        rr[tid] = acc * rs128;
    }
    __syncthreads();

    if (tid < MUL) {
        float acc = 0.f;
        for (int j = 0; j < NRAD; ++j) acc += rr[j] * wm1[j * MUL + tid];
        float x = acc * rs64;
        hh[tid] = fmaxf(x, 0.f) + log1pf(expf(-fabsf(x)));   // stable softplus
    }
    __syncthreads();

    if (tid < NRAD) {
        float acc = 0.f;
        for (int k = 0; k < MUL; ++k) acc += hh[k] * wm2[k * NRAD + tid];
        float v = acc * rs128;
        rl[tid]  = v;
        sRC[tid] = v * 0.28209479177387814f;      // * B00 = 1/sqrt(4pi)
        if (bt == 0) out3[g * NRAD + tid] = v;
    }

    // ---- angular coefficients (reads global only; rl/sRC covered by next sync) ----
    const float* WA[6] = {wa0, wa1, wa2, wa3, wa4, wa5};
    for (int t = tid; t < NCH * SH_DIM; t += 256) {
        int c = t / SH_DIM, kk = t % SH_DIM;
        int l = 0;
        while ((l + 1) * (l + 1) <= kk) ++l;
        int j = kk - l * l;
        int d = 2 * l + 1;
        const float* w  = WA[l];
        const float* nb = ne + (size_t)fi * EMB_DIM + MUL * l * l + j;
        const float* sb = sp + ts * NIRR + MUL * l;
        float acc = 0.f;
        for (int k = 0; k < MUL; ++k) acc += nb[k * d] * sb[k] * w[k * NCH + c];
        sang[t] = acc * rs128;
    }
    __syncthreads();

    // ---- Fourier coefficients: 4 betas x 4 ch x 11 = 176 threads ----
    if (tid < BTILE * NCH * 11) {
        int b = tid / (NCH * 11);
        int rem = tid % (NCH * 11);
        int c = rem / 11, j = rem % 11;
        const float* W = sW[b];
        float acc = 0.f;
        if (j == 0) {
            for (int l = 0; l <= LMAX; ++l)
                acc += sang[c * SH_DIM + l * l + l] * W[l * (l + 1) / 2];
        } else if (j <= 5) {
            int m = j;
            for (int l = m; l <= LMAX; ++l)
                acc += sang[c * SH_DIM + l * l + l + m] * W[l * (l + 1) / 2 + m];
        } else {
            int m = j - 5;
            for (int l = m; l <= LMAX; ++l)
                acc += sang[c * SH_DIM + l * l + l - m] * W[l * (l + 1) / 2 + m];
        }
        sF[b][c][j] = acc;
    }

    // ---- out0 (only the 16 bt==0 blocks): coeffs[g,c,r,kk] ----
    if (bt == 0) {
        for (int t = tid; t < NCH * NRAD * SH_DIM; t += 256) {
            int kk = t % SH_DIM;
            int r  = (t / SH_DIM) % NRAD;
            int c  = t / (SH_DIM * NRAD);
            float v = sang[c * SH_DIM + kk];
            if (kk == 0) v += rl[r];
            out0[(size_t)g * (NCH * NRAD * SH_DIM) + t] = v;
        }
    }
    __syncthreads();

    // ---- logsumexp synthesis for the 4 beta rows ----
    const float dalpha = 6.283185307179586f / 359.0f;
    for (int t = tid; t < BTILE * RALPHA; t += 256) {
        int b = t / RALPHA;
        int a = t % RALPHA;
        float alpha = dalpha * (float)a;
        float s1, c1;
        __sincosf(alpha, &s1, &c1);
        float t0 = sF[b][0][0], t1 = sF[b][1][0], t2 = sF[b][2][0], t3 = sF[b][3][0];
        float cm = c1, sm = s1;
        for (int m = 1; m <= 5; ++m) {
            t0 += sF[b][0][m] * cm + sF[b][0][5 + m] * sm;
            t1 += sF[b][1][m] * cm + sF[b][1][5 + m] * sm;
            t2 += sF[b][2][m] * cm + sF[b][2][5 + m] * sm;
            t3 += sF[b][3][m] * cm + sF[b][3][5 + m] * sm;
            float cn = cm * c1 - sm * s1;
            float sn = sm * c1 + cm * s1;
            cm = cn; sm = sn;
        }
        float mx = fmaxf(fmaxf(t0, t1), fmaxf(t2, t3));
        float s = expf(t0 - mx) + expf(t1 - mx) + expf(t2 - mx) + expf(t3 - mx);
        sL[t] = mx + logf(s);          // [b][a] contiguous == (beta,alpha) order
    }
    __syncthreads();

    const vfloat4* srcL = (const vfloat4*)sL;            // 359 float4s
    const int N4 = (BTILE * RALPHA) / 4;                 // 359

    // out2 tile (1436 floats, 16B-aligned since bt*1436*4B % 16 == 0)
    {
        vfloat4* dst2 = (vfloat4*)(out2 + (size_t)g * GRID_BA + bt * (BTILE * RALPHA));
        for (int t = tid; t < N4; t += 256)
            dst2[t] = srcL[t];
    }
    // out1: r-outer, each r is one contiguous aligned 5744-B burst
    float* base1 = out1 + (size_t)g * NRAD * GRID_BA + bt * (BTILE * RALPHA);
    for (int r = 0; r < NRAD; ++r) {
        const float rc = sRC[r];
        vfloat4* dst = (vfloat4*)(base1 + (size_t)r * GRID_BA);
        for (int t = tid; t < N4; t += 256)
            dst[t] = srcL[t] + rc;
    }
}

// ---------------------------------------------------------------------------
extern "C" void kernel_launch(void* const* d_in, const int* in_sizes, int n_in,
                              void* d_out, int out_size, void* d_ws, size_t ws_size,
                              hipStream_t stream) {
    const float* ne   = (const float*)d_in[0];
    const float* sp   = (const float*)d_in[1];
    const float* wrad = (const float*)d_in[2];
    const float* wm1  = (const float*)d_in[3];
    const float* wm2  = (const float*)d_in[4];
    const float* wa0  = (const float*)d_in[5];
    const float* wa1  = (const float*)d_in[6];
    const float* wa2  = (const float*)d_in[7];
    const float* wa3  = (const float*)d_in[8];
    const float* wa4  = (const float*)d_in[9];
    const float* wa5  = (const float*)d_in[10];
    const int* focus  = (const int*)d_in[11];
    const int* tspec  = (const int*)d_in[12];

    float* out  = (float*)d_out;
    float* out0 = out + OUT0_OFF;
    float* out1 = out + OUT1_OFF;
    float* out2 = out + OUT2_OFF;
    float* out3 = out + OUT3_OFF;

    float* tab = (float*)((char*)d_ws + WS_TAB_OFF);

    hipLaunchKernelGGL(k_tab, dim3(1), dim3(256), 0, stream, tab);
    hipLaunchKernelGGL(k_all, dim3(NBT, NGRAPH), dim3(256), 0, stream,
                       tab, ne, sp, wrad, wm1, wm2, wa0, wa1, wa2, wa3, wa4, wa5,
                       focus, tspec, out0, out1, out2, out3);
}

// Round 8
// 340.553 us; speedup vs baseline: 1.0480x; 1.0480x over previous
//
#include <hip/hip_runtime.h>
#include <math.h>

#define LMAX   5
#define MUL    128
#define NCH    4
#define NRAD   64
#define RBETA  180
#define RALPHA 359
#define NGRAPH 16
#define SH_DIM 36
#define EMB_DIM 4608
#define NIRR   768

#define GRID_BA (RBETA * RALPHA)          // 64620
#define NW21    21                        // (LMAX+1)(LMAX+2)/2 packed (l,m) weights
#define BTILE   4                         // beta rows per fused block; 4*359 floats = 359 float4 exactly
#define NBT     (RBETA / BTILE)           // 45

typedef float vfloat4 __attribute__((ext_vector_type(4)));

// out layout (floats): [0] coeffs 147456 | [1] pos 66170880 | [2] ang 1033920 | [3] rad 1024
#define OUT0_OFF 0
#define OUT1_OFF 147456
#define OUT2_OFF (147456 + 66170880)
#define OUT3_OFF (147456 + 66170880 + 1033920)

// ws layout (bytes):
//   float tab[180*21]  @ 0      (15120 B, padded to 15360)
//   float ang[16][144] @ 15360  (9216 B)
//   float rad[16][64]  @ 24576  (4096 B)
#define WS_TAB_OFF 0
#define WS_ANG_OFF 15360
#define WS_RAD_OFF 24576

// ---------------------------------------------------------------------------
// K1: per-graph small path (blocks 0..15) + SH weight-table init (block 16).
__global__ __launch_bounds__(256)
void k_small(const float* __restrict__ ne, const float* __restrict__ sp,
             const float* __restrict__ wrad, const float* __restrict__ wm1,
             const float* __restrict__ wm2,
             const float* __restrict__ wa0, const float* __restrict__ wa1,
             const float* __restrict__ wa2, const float* __restrict__ wa3,
             const float* __restrict__ wa4, const float* __restrict__ wa5,
             const int* __restrict__ focus, const int* __restrict__ tspec,
             float* __restrict__ out0, float* __restrict__ out3,
             float* __restrict__ ang_ws, float* __restrict__ rad_ws,
             float* __restrict__ tab)
{
    const int tid = threadIdx.x;

    if (blockIdx.x == NGRAPH) {
        // ---- table-init block: thread i owns GL node i (independent Newton) ----
        __shared__ double rcp[RBETA];     // 1/(k+1)
        for (int k = tid; k < RBETA; k += 256) rcp[k] = 1.0 / (double)(k + 1);
        __syncthreads();
        const int i = tid;
        if (i >= RBETA) return;
        const double PI = 3.14159265358979323846;
        double x = -cos(PI * (i + 0.75) / (RBETA + 0.5));   // ascending node guess
        for (int it = 0; it < 4; ++it) {                    // 2 iters reach fp64 eps; 4 = margin
            double p0 = 1.0, p1 = x;
            for (int k = 1; k < RBETA; ++k) {
                double p2 = ((2.0 * k + 1.0) * x * p1 - (double)k * p0) * rcp[k];
                p0 = p1; p1 = p2;
            }
            double dp = RBETA * (x * p1 - p0) / (x * x - 1.0);
            x -= p1 / dp;
        }
        double P[LMAX + 1][LMAX + 1];
        P[0][0] = 1.0;
        double somx2 = sqrt(fmax(1.0 - x * x, 0.0));
        for (int m = 1; m <= LMAX; ++m) P[m][m] = -(2.0 * m - 1.0) * somx2 * P[m - 1][m - 1];
        for (int m = 0; m < LMAX; ++m)  P[m + 1][m] = (2.0 * m + 1.0) * x * P[m][m];
        for (int m = 0; m <= LMAX; ++m)
            for (int l = m + 2; l <= LMAX; ++l)
                P[l][m] = ((2.0 * l - 1.0) * x * P[l - 1][m] - (l + m - 1.0) * P[l - 2][m]) / (double)(l - m);
        const double FOURPI = 12.566370614359172;
        for (int l = 0; l <= LMAX; ++l) {
            for (int m = 0; m <= l; ++m) {
                double fr = 1.0;                       // (l-m)!/(l+m)!
                for (int k = l - m + 1; k <= l + m; ++k) fr /= (double)k;
                double N = sqrt((2.0 * l + 1.0) / FOURPI * fr);
                double w = N * P[l][m];
                if (m > 0) w *= 1.4142135623730951;
                tab[i * NW21 + l * (l + 1) / 2 + m] = (float)w;
            }
        }
        return;
    }

    // ---- per-graph small path ----
    __shared__ float s0[MUL];
    __shared__ float rr[NRAD];
    __shared__ float hh[MUL];
    __shared__ float rl[NRAD];
    __shared__ float sang[NCH * SH_DIM];

    const int g = blockIdx.x;
    const int fi = focus[g];
    const int ts = tspec[g];
    const float rs128 = 0.08838834764831845f;   // 1/sqrt(128)
    const float rs64  = 0.125f;                 // 1/sqrt(64)

    if (tid < MUL) s0[tid] = ne[(size_t)fi * EMB_DIM + tid] * sp[ts * NIRR + tid];
    __syncthreads();

    if (tid < NRAD) {
        float acc = 0.f;
        for (int k = 0; k < MUL; ++k) acc += s0[k] * wrad[k * NRAD + tid];
        rr[tid] = acc * rs128;
    }
    __syncthreads();

    if (tid < MUL) {
        float acc = 0.f;
        for (int j = 0; j < NRAD; ++j) acc += rr[j] * wm1[j * MUL + tid];
        float x = acc * rs64;
        hh[tid] = fmaxf(x, 0.f) + log1pf(expf(-fabsf(x)));   // stable softplus
    }
    __syncthreads();

    if (tid < NRAD) {
        float acc = 0.f;
        for (int k = 0; k < MUL; ++k) acc += hh[k] * wm2[k * NRAD + tid];
        float v = acc * rs128;
        rl[tid] = v;
        out3[g * NRAD + tid] = v;
        rad_ws[g * NRAD + tid] = v;
    }

    // angular coefficients: ang[c][l*l + j] = rs128 * sum_k ne_blk[k][j]*spec[k]*W_l[k][c]
    const float* WA[6] = {wa0, wa1, wa2, wa3, wa4, wa5};
    for (int t = tid; t < NCH * SH_DIM; t += blockDim.x) {
        int c = t / SH_DIM, kk = t % SH_DIM;
        int l = 0;
        while ((l + 1) * (l + 1) <= kk) ++l;
        int j = kk - l * l;
        int d = 2 * l + 1;
        const float* w  = WA[l];
        const float* nb = ne + (size_t)fi * EMB_DIM + MUL * l * l + j;
        const float* sb = sp + ts * NIRR + MUL * l;
        float acc = 0.f;
        for (int k = 0; k < MUL; ++k) acc += nb[k * d] * sb[k] * w[k * NCH + c];
        float v = acc * rs128;
        sang[t] = v;
        ang_ws[g * (NCH * SH_DIM) + t] = v;
    }
    __syncthreads();

    // log_position_coeffs[g,c,r,kk] = ang[c,kk] + (kk==0 ? rad[r] : 0)
    for (int t = tid; t < NCH * NRAD * SH_DIM; t += blockDim.x) {
        int kk = t % SH_DIM;
        int r  = (t / SH_DIM) % NRAD;
        int c  = t / (SH_DIM * NRAD);
        float v = sang[c * SH_DIM + kk];
        if (kk == 0) v += rl[r];
        out0[(size_t)g * (NCH * NRAD * SH_DIM) + t] = v;
    }
}

// ---------------------------------------------------------------------------
// K2 (fused): one block per (beta-tile of 4, graph).
// Phase 1: Fourier coeffs for the 4 beta rows (from tab + ang_ws).
// Phase 2: logsumexp over channels for 4*359 grid points -> LDS.
// Phase 3: stream out2 tile (1436 floats = 359 float4, aligned) and out1 for
//          all 64 radii (64 contiguous 5744-B float4 bursts, regular cached
//          stores -- R4 showed nt/bypass-L2 costs ~20 us; L2 write-coalescing
//          is what gets us fill-level write BW).
__global__ __launch_bounds__(256)
void k_fused(const float* __restrict__ tab, const float* __restrict__ ang_ws,
             const float* __restrict__ rad_ws,
             float* __restrict__ out1, float* __restrict__ out2)
{
    __shared__ float sW[BTILE][NW21];
    __shared__ float sAng[NCH * SH_DIM];
    __shared__ float sF[BTILE][NCH][11];
    __shared__ float sRC[NRAD];
    __shared__ __align__(16) float sL[BTILE * RALPHA];   // 1436 floats

    const int bt  = blockIdx.x;          // 0..44
    const int g   = blockIdx.y;
    const int tid = threadIdx.x;

    if (tid < BTILE * NW21)              // 84 threads
        sW[tid / NW21][tid % NW21] = tab[(bt * BTILE + tid / NW21) * NW21 + tid % NW21];
    if (tid >= 128 && tid < 128 + NRAD)
        sRC[tid - 128] = rad_ws[g * NRAD + (tid - 128)] * 0.28209479177387814f; // B00
    for (int t = tid; t < NCH * SH_DIM; t += 256)
        sAng[t] = ang_ws[g * (NCH * SH_DIM) + t];
    __syncthreads();

    // Fourier coefficients: 4 betas x 4 ch x 11 = 176 threads
    if (tid < BTILE * NCH * 11) {
        int b = tid / (NCH * 11);
        int rem = tid % (NCH * 11);
        int c = rem / 11, j = rem % 11;
        const float* W = sW[b];
        float acc = 0.f;
        if (j == 0) {
            for (int l = 0; l <= LMAX; ++l)
                acc += sAng[c * SH_DIM + l * l + l] * W[l * (l + 1) / 2];
        } else if (j <= 5) {
            int m = j;
            for (int l = m; l <= LMAX; ++l)
                acc += sAng[c * SH_DIM + l * l + l + m] * W[l * (l + 1) / 2 + m];
        } else {
            int m = j - 5;
            for (int l = m; l <= LMAX; ++l)
                acc += sAng[c * SH_DIM + l * l + l - m] * W[l * (l + 1) / 2 + m];
        }
        sF[b][c][j] = acc;
    }
    __syncthreads();

    // logsumexp synthesis for the 4 rows
    const float dalpha = 6.283185307179586f / 359.0f;
    for (int t = tid; t < BTILE * RALPHA; t += 256) {
        int b = t / RALPHA;
        int a = t % RALPHA;
        float alpha = dalpha * (float)a;
        float s1, c1;
        __sincosf(alpha, &s1, &c1);
        float t0 = sF[b][0][0], t1 = sF[b][1][0], t2 = sF[b][2][0], t3 = sF[b][3][0];
        float cm = c1, sm = s1;
        for (int m = 1; m <= 5; ++m) {
            t0 += sF[b][0][m] * cm + sF[b][0][5 + m] * sm;
            t1 += sF[b][1][m] * cm + sF[b][1][5 + m] * sm;
            t2 += sF[b][2][m] * cm + sF[b][2][5 + m] * sm;
            t3 += sF[b][3][m] * cm + sF[b][3][5 + m] * sm;
            float cn = cm * c1 - sm * s1;
            float sn = sm * c1 + cm * s1;
            cm = cn; sm = sn;
        }
        float mx = fmaxf(fmaxf(t0, t1), fmaxf(t2, t3));
        float s = expf(t0 - mx) + expf(t1 - mx) + expf(t2 - mx) + expf(t3 - mx);
        sL[t] = mx + logf(s);          // [b][a] contiguous == (beta,alpha) order
    }
    __syncthreads();

    const vfloat4* srcL = (const vfloat4*)sL;            // 359 float4s
    const int N4 = (BTILE * RALPHA) / 4;                 // 359

    // out2 tile
    {
        vfloat4* dst2 = (vfloat4*)(out2 + (size_t)g * GRID_BA + bt * (BTILE * RALPHA));
        for (int t = tid; t < N4; t += 256)
            dst2[t] = srcL[t];
    }
    // out1: r-outer, each r is one contiguous aligned 5744-B burst
    float* base1 = out1 + (size_t)g * NRAD * GRID_BA + bt * (BTILE * RALPHA);
    for (int r = 0; r < NRAD; ++r) {
        const float rc = sRC[r];
        vfloat4* dst = (vfloat4*)(base1 + (size_t)r * GRID_BA);
        for (int t = tid; t < N4; t += 256)
            dst[t] = srcL[t] + rc;
    }
}

// ---------------------------------------------------------------------------
extern "C" void kernel_launch(void* const* d_in, const int* in_sizes, int n_in,
                              void* d_out, int out_size, void* d_ws, size_t ws_size,
                              hipStream_t stream) {
    const float* ne   = (const float*)d_in[0];
    const float* sp   = (const float*)d_in[1];
    const float* wrad = (const float*)d_in[2];
    const float* wm1  = (const float*)d_in[3];
    const float* wm2  = (const float*)d_in[4];
    const float* wa0  = (const float*)d_in[5];
    const float* wa1  = (const float*)d_in[6];
    const float* wa2  = (const float*)d_in[7];
    const float* wa3  = (const float*)d_in[8];
    const float* wa4  = (const float*)d_in[9];
    const float* wa5  = (const float*)d_in[10];
    const int* focus  = (const int*)d_in[11];
    const int* tspec  = (const int*)d_in[12];

    float* out  = (float*)d_out;
    float* out0 = out + OUT0_OFF;
    float* out1 = out + OUT1_OFF;
    float* out2 = out + OUT2_OFF;
    float* out3 = out + OUT3_OFF;

    float* tab    = (float*)((char*)d_ws + WS_TAB_OFF);
    float* ang_ws = (float*)((char*)d_ws + WS_ANG_OFF);
    float* rad_ws = (float*)((char*)d_ws + WS_RAD_OFF);

    // blocks 0..15: per-graph path; block 16: parallel SH-table init
    hipLaunchKernelGGL(k_small, dim3(NGRAPH + 1), dim3(256), 0, stream,
                       ne, sp, wrad, wm1, wm2, wa0, wa1, wa2, wa3, wa4, wa5,
                       focus, tspec, out0, out3, ang_ws, rad_ws, tab);
    hipLaunchKernelGGL(k_fused, dim3(NBT, NGRAPH), dim3(256), 0, stream,
                       tab, ang_ws, rad_ws, out1, out2);
}